// Round 19
// baseline (175.357 us; speedup 1.0000x reference)
//
#include <hip/hip_runtime.h>

typedef __attribute__((ext_vector_type(8))) __bf16 bf16x8;
typedef __attribute__((ext_vector_type(4))) float f32x4;

__device__ __forceinline__ unsigned short f2bf(float f) {
  __bf16 h = (__bf16)f;
  return __builtin_bit_cast(unsigned short, h);
}

__device__ __forceinline__ f32x4 mfma_bf16(bf16x8 a, bf16x8 b, f32x4 c) {
  return __builtin_amdgcn_mfma_f32_16x16x32_bf16(a, b, c, 0, 0, 0);
}

__device__ __forceinline__ void gload_lds16(const void* g, void* l) {
  __builtin_amdgcn_global_load_lds((const __attribute__((address_space(1))) void*)g,
                                   (__attribute__((address_space(3))) void*)l, 16, 0, 0);
}

// ---------------- fused prep: x-cvt + 4-weight cvt + er transpose ----------------
// blocks [0,4096): x f32->bf16 ; [4096,8192): weights ; [8192,8448): er transpose
// er is pre-scaled by 1/sqrt(h) = 1/32 (S scale folded into producers).

__global__ void prep_all(const float* __restrict__ x,
                         const float* __restrict__ Wq, const float* __restrict__ Wk,
                         const float* __restrict__ Wv, const float* __restrict__ Wo,
                         const float* __restrict__ er,
                         unsigned short* __restrict__ xb,
                         unsigned short* __restrict__ Wqb, unsigned short* __restrict__ Wkb,
                         unsigned short* __restrict__ Wvb, unsigned short* __restrict__ Wob,
                         unsigned short* __restrict__ ert)
{
  const int bid = blockIdx.x, tid = threadIdx.x;
  if (bid < 4096) {
    int i = bid * 256 + tid;
    float4 v = reinterpret_cast<const float4*>(x)[i];
    ushort4 o;
    o.x = f2bf(v.x); o.y = f2bf(v.y); o.z = f2bf(v.z); o.w = f2bf(v.w);
    reinterpret_cast<ushort4*>(xb)[i] = o;
  } else if (bid < 8192) {
    int i = (bid - 4096) * 256 + tid;            // 1048576 total
    int which = i >> 18, j = i & 262143;
    const float* src = (which == 0) ? Wq : (which == 1) ? Wk : (which == 2) ? Wv : Wo;
    unsigned short* dst = (which == 0) ? Wqb : (which == 1) ? Wkb : (which == 2) ? Wvb : Wob;
    float4 v = reinterpret_cast<const float4*>(src)[j];
    ushort4 o;
    o.x = f2bf(v.x); o.y = f2bf(v.y); o.z = f2bf(v.z); o.w = f2bf(v.w);
    reinterpret_cast<ushort4*>(dst)[j] = o;
  } else {
    __shared__ float t[32][33];
    int blk = bid - 8192;                        // 256 blocks: 64 w-tiles x 4 d-tiles
    int w0 = (blk & 63) * 32, d0 = (blk >> 6) * 32;
    int tx = tid & 31, ty = tid >> 5;            // 32 x 8
#pragma unroll
    for (int i = 0; i < 4; ++i)
      t[ty + i * 8][tx] = er[(size_t)(d0 + ty + i * 8) * 2048 + w0 + tx];
    __syncthreads();
#pragma unroll
    for (int i = 0; i < 4; ++i)
      ert[(size_t)(w0 + ty + i * 8) * 128 + d0 + tx] = f2bf(t[tx][ty + i * 8] * 0.03125f);
  }
}

// ---------------- 3-in-1 QKV projection GEMM ----------------
// K output pre-scaled by 1/32 (attention S scale folded here).

__global__ __launch_bounds__(512, 1) void gemm_qkv3(
    const unsigned short* __restrict__ xb,
    const unsigned short* __restrict__ Wqb, const unsigned short* __restrict__ Wkb,
    const unsigned short* __restrict__ Wvb,
    const float* __restrict__ bq, const float* __restrict__ bk, const float* __restrict__ bvv,
    unsigned short* __restrict__ Qb, unsigned short* __restrict__ Kb,
    unsigned short* __restrict__ Vtb)
{
  __shared__ __align__(16) char lds[131072];   // buf: A@0 BQ@16K BK@32K BV@48K, x2

  const int tid = threadIdx.x;
  const int lane = tid & 63, wid = tid >> 6;
  const int lr = lane & 15, lq = lane >> 4;
  const int wr = wid >> 1, wc = wid & 1;       // 4M x 2N wave grid
  const int i0 = blockIdx.x * 128, j0 = blockIdx.y * 128;

  f32x4 aQ[2][4] = {}, aK[2][4] = {}, aV[2][4] = {};

  int ldso[2];
  const char *asrc[2], *qsrc[2], *ksrc[2], *vsrc[2];
#pragma unroll
  for (int p = 0; p < 2; ++p) {
    int L = p * 8192 + tid * 16;
    int row = L >> 7, colb = L & 127;
    int sc = colb ^ ((row & 7) << 4);
    ldso[p] = L;
    asrc[p] = (const char*)xb  + (size_t)(i0 + row) * 2048 + sc;
    qsrc[p] = (const char*)Wqb + (size_t)(j0 + row) * 2048 + sc;
    ksrc[p] = (const char*)Wkb + (size_t)(j0 + row) * 2048 + sc;
    vsrc[p] = (const char*)Wvb + (size_t)(j0 + row) * 2048 + sc;
  }

#pragma unroll
  for (int p = 0; p < 2; ++p) gload_lds16(asrc[p], lds + ldso[p]);
#pragma unroll
  for (int p = 0; p < 2; ++p) gload_lds16(qsrc[p], lds + 16384 + ldso[p]);
#pragma unroll
  for (int p = 0; p < 2; ++p) gload_lds16(ksrc[p], lds + 32768 + ldso[p]);
#pragma unroll
  for (int p = 0; p < 2; ++p) gload_lds16(vsrc[p], lds + 49152 + ldso[p]);

  const int swz = (lr & 7) << 4;

  for (int kt = 0; kt < 16; ++kt) {
    char* cb = lds + (kt & 1) * 65536;
    char* nb = lds + ((kt + 1) & 1) * 65536;

    asm volatile("s_waitcnt vmcnt(0)" ::: "memory");
    __builtin_amdgcn_sched_barrier(0);
    __builtin_amdgcn_s_barrier();
    __builtin_amdgcn_sched_barrier(0);

    if (kt < 15) {
      const int k0b = (kt + 1) * 128;
#pragma unroll
      for (int p = 0; p < 2; ++p) gload_lds16(asrc[p] + k0b, nb + ldso[p]);
#pragma unroll
      for (int p = 0; p < 2; ++p) gload_lds16(qsrc[p] + k0b, nb + 16384 + ldso[p]);
#pragma unroll
      for (int p = 0; p < 2; ++p) gload_lds16(ksrc[p] + k0b, nb + 32768 + ldso[p]);
#pragma unroll
      for (int p = 0; p < 2; ++p) gload_lds16(vsrc[p] + k0b, nb + 49152 + ldso[p]);
    }
    __builtin_amdgcn_sched_barrier(0);

#pragma unroll
    for (int kk = 0; kk < 2; ++kk) {
      const int coff = (kk * 64 + lq * 16) ^ swz;
      bf16x8 af[2];
#pragma unroll
      for (int m = 0; m < 2; ++m)
        af[m] = *(const bf16x8*)(cb + (wr * 32 + m * 16 + lr) * 128 + coff);
      bf16x8 bq_[4], bk_[4], bv_[4];
#pragma unroll
      for (int n = 0; n < 4; ++n) {
        const int rb = (wc * 64 + n * 16 + lr) * 128 + coff;
        bq_[n] = *(const bf16x8*)(cb + 16384 + rb);
        bk_[n] = *(const bf16x8*)(cb + 32768 + rb);
        bv_[n] = *(const bf16x8*)(cb + 49152 + rb);
      }
      __builtin_amdgcn_s_setprio(1);
#pragma unroll
      for (int m = 0; m < 2; ++m)
#pragma unroll
        for (int n = 0; n < 4; ++n) {
          aQ[m][n] = mfma_bf16(af[m], bq_[n], aQ[m][n]);
          aK[m][n] = mfma_bf16(af[m], bk_[n], aK[m][n]);
          aV[m][n] = mfma_bf16(af[m], bv_[n], aV[m][n]);
        }
      __builtin_amdgcn_s_setprio(0);
    }
  }

  float vbq[4], vbk[4], vbv[4];
#pragma unroll
  for (int n = 0; n < 4; ++n) {
    int gj = j0 + wc * 64 + n * 16 + lr;
    vbq[n] = bq[gj]; vbk[n] = bk[gj]; vbv[n] = bvv[gj];
  }

#pragma unroll
  for (int m = 0; m < 2; ++m)
#pragma unroll
    for (int n = 0; n < 4; ++n)
#pragma unroll
      for (int r = 0; r < 4; ++r) {
        int gi = i0 + wr * 32 + m * 16 + lq * 4 + r;
        int gj = j0 + wc * 64 + n * 16 + lr;
        Qb[(size_t)gi * 1024 + gj] = f2bf(aQ[m][n][r] + vbq[n]);
        Kb[(size_t)gi * 1024 + gj] = f2bf((aK[m][n][r] + vbk[n]) * 0.03125f);
      }

  __syncthreads();
  unsigned short* lds16 = (unsigned short*)lds;
#pragma unroll
  for (int m = 0; m < 2; ++m)
#pragma unroll
    for (int n = 0; n < 4; ++n)
#pragma unroll
      for (int r = 0; r < 4; ++r) {
        int il = wr * 32 + m * 16 + lq * 4 + r;
        int jl = wc * 64 + n * 16 + lr;
        lds16[jl * 132 + il] = f2bf(aV[m][n][r] + vbv[n]);
      }
  __syncthreads();
  {
    const int b = i0 >> 11, w0 = i0 & 2047, bd = j0 >> 7;
    for (int idx = tid; idx < 16384; idx += 512) {
      int dl = idx >> 7, wl = idx & 127;
      Vtb[(size_t)((b * 8 + bd) * 128 + dl) * 2048 + w0 + wl] = lds16[dl * 132 + wl];
    }
  }
}

// ---------------- Wo GEMM (R18 structure, verbatim) ----------------

__global__ __launch_bounds__(512, 4) void gemm_bt(
    const unsigned short* __restrict__ A,
    const unsigned short* __restrict__ Bt,
    const float* __restrict__ bias,
    float* __restrict__ C)
{
  __shared__ __align__(16) char lds[65536];    // buf: A@0 B@16K, x2 @32K

  const int tid = threadIdx.x;
  const int lane = tid & 63, wid = tid >> 6;
  const int lr = lane & 15, lq = lane >> 4;
  const int wr = wid >> 1, wc = wid & 1;       // 4M x 2N wave grid
  const int i0 = blockIdx.x * 128, j0 = blockIdx.y * 128;

  f32x4 acc[2][4] = {};

  int ldso[2];
  const char *asrc[2], *bsrc[2];
#pragma unroll
  for (int p = 0; p < 2; ++p) {
    int L = p * 8192 + tid * 16;
    int row = L >> 7, colb = L & 127;
    int sc = colb ^ ((row & 7) << 4);
    ldso[p] = L;
    asrc[p] = (const char*)A  + (size_t)(i0 + row) * 2048 + sc;
    bsrc[p] = (const char*)Bt + (size_t)(j0 + row) * 2048 + sc;
  }

#pragma unroll
  for (int p = 0; p < 2; ++p) gload_lds16(asrc[p], lds + ldso[p]);
#pragma unroll
  for (int p = 0; p < 2; ++p) gload_lds16(bsrc[p], lds + 16384 + ldso[p]);

  const int swz = (lr & 7) << 4;

  for (int kt = 0; kt < 16; ++kt) {
    char* cb = lds + (kt & 1) * 32768;
    char* nb = lds + ((kt + 1) & 1) * 32768;

    asm volatile("s_waitcnt vmcnt(0)" ::: "memory");
    __builtin_amdgcn_sched_barrier(0);
    __builtin_amdgcn_s_barrier();
    __builtin_amdgcn_sched_barrier(0);

    if (kt < 15) {
      const int k0b = (kt + 1) * 128;
#pragma unroll
      for (int p = 0; p < 2; ++p) gload_lds16(asrc[p] + k0b, nb + ldso[p]);
#pragma unroll
      for (int p = 0; p < 2; ++p) gload_lds16(bsrc[p] + k0b, nb + 16384 + ldso[p]);
    }
    __builtin_amdgcn_sched_barrier(0);

#pragma unroll
    for (int kk = 0; kk < 2; ++kk) {
      const int coff = (kk * 64 + lq * 16) ^ swz;
      bf16x8 af[2];
#pragma unroll
      for (int m = 0; m < 2; ++m)
        af[m] = *(const bf16x8*)(cb + (wr * 32 + m * 16 + lr) * 128 + coff);
      bf16x8 bf_[4];
#pragma unroll
      for (int n = 0; n < 4; ++n)
        bf_[n] = *(const bf16x8*)(cb + 16384 + (wc * 64 + n * 16 + lr) * 128 + coff);
      __builtin_amdgcn_s_setprio(1);
#pragma unroll
      for (int m = 0; m < 2; ++m)
#pragma unroll
        for (int n = 0; n < 4; ++n)
          acc[m][n] = mfma_bf16(af[m], bf_[n], acc[m][n]);
      __builtin_amdgcn_s_setprio(0);
    }
  }

  float bv[4];
#pragma unroll
  for (int n = 0; n < 4; ++n) bv[n] = bias[j0 + wc * 64 + n * 16 + lr];
#pragma unroll
  for (int m = 0; m < 2; ++m)
#pragma unroll
    for (int n = 0; n < 4; ++n)
#pragma unroll
      for (int r = 0; r < 4; ++r) {
        int gi = i0 + wr * 32 + m * 16 + lq * 4 + r;
        int gj = j0 + wc * 64 + n * 16 + lr;
        C[(size_t)gi * 1024 + gj] = acc[m][n][r] + bv[n];
      }
}

// ---------------- fused attention (R15 pipeline; serial-chain polish) ----------------
// K and er arrive pre-scaled by 1/32 -> S comes out of MFMA already scaled
// (scale pass deleted). exp via exp2(fma(s,L2E,-M*L2E)). rsum cross-lane
// reduction moved after PV (hides the 4-shfl dependency chain under MFMA).

__global__ __launch_bounds__(512) void attn_fused(
    const unsigned short* __restrict__ Qb,
    const unsigned short* __restrict__ Kb,
    const unsigned short* __restrict__ Vt,
    const unsigned short* __restrict__ ErT,
    float* __restrict__ a_out,
    unsigned short* __restrict__ ctx)
{
  __shared__ __align__(16) char Klb[32768];  // K[kj] [128][256B] swz
  __shared__ __align__(16) char Qlb[32768];  // Q[kj] [128][256B] swz
  __shared__ __align__(16) char Vlb[32768];  // Vt    [128][256B] swz
  __shared__ __align__(16) char Plb[32768];  // P     [128][256B] swz

  const float L2E = 1.4426950408889634f;

  const int bb = blockIdx.x;                 // b*8+band
  const int bd = bb & 7, b = bb >> 3;
  const int qi0 = blockIdx.y * 128;
  const int tid = threadIdx.x, wid = tid >> 6, lane = tid & 63;
  const int lr = lane & 15, lq = lane >> 4;

  bf16x8 qf[4], ef[4];
  {
    const unsigned short* Qrow = Qb + (size_t)(b * 2048 + qi0 + wid * 16 + lr) * 1024 + bd * 128;
    const unsigned short* Erow = ErT + (size_t)(qi0 + wid * 16 + lr) * 128;
#pragma unroll
    for (int kk = 0; kk < 4; ++kk) {
      qf[kk] = *(const bf16x8*)(Qrow + kk * 32 + lq * 8);
      ef[kk] = *(const bf16x8*)(Erow + kk * 32 + lq * 8);
    }
  }

  int ldso[4];
  const char *ksrc[4], *qsrc[4], *vsrc[4];
#pragma unroll
  for (int p = 0; p < 4; ++p) {
    int L = p * 8192 + tid * 16;
    int row = L >> 8, cs = L & 255;
    int sc = cs ^ ((row & 7) << 4);
    ldso[p] = L;
    ksrc[p] = (const char*)Kb + ((size_t)(b * 2048 + row) * 1024 + bd * 128) * 2 + sc;
    qsrc[p] = (const char*)Qb + ((size_t)(b * 2048 + row) * 1024 + bd * 128) * 2 + sc;
    vsrc[p] = (const char*)Vt + ((size_t)(bb * 128 + row) * 2048) * 2 + sc;
  }

  // prologue: stage tile 0, drain everything once (iter-0 safety)
#pragma unroll
  for (int p = 0; p < 4; ++p) gload_lds16(ksrc[p], Klb + ldso[p]);
#pragma unroll
  for (int p = 0; p < 4; ++p) gload_lds16(qsrc[p], Qlb + ldso[p]);
#pragma unroll
  for (int p = 0; p < 4; ++p) gload_lds16(vsrc[p], Vlb + ldso[p]);
  asm volatile("s_waitcnt vmcnt(0)" ::: "memory");
  __builtin_amdgcn_sched_barrier(0);

  f32x4 oacc[8] = {};
  float M[4], L[4];
#pragma unroll
  for (int r = 0; r < 4; ++r) { M[r] = -1e30f; L[r] = 0.f; }

  float* abase = a_out + (size_t)bb * 2048 * 2048;

  for (int kt = 0; kt < 16; ++kt) {
    const int kj0 = kt * 128;
    const size_t nkq = (size_t)((kt + 1) & 15) * 262144;
    const size_t nv = (size_t)((kt + 1) & 15) * 256;

    // own KQ(t) landed (32 stores + 4 V may remain in flight); rendezvous
    asm volatile("s_waitcnt vmcnt(36)" ::: "memory");
    __builtin_amdgcn_sched_barrier(0);
    __builtin_amdgcn_s_barrier();
    __builtin_amdgcn_sched_barrier(0);

    f32x4 sacc[8] = {};
    __builtin_amdgcn_s_setprio(1);
#pragma unroll
    for (int kk = 0; kk < 4; ++kk) {
#pragma unroll
      for (int nf = 0; nf < 8; ++nf) {
        const int row = nf * 16 + lr;
        bf16x8 kf = *(const bf16x8*)(Klb + row * 256 + ((kk * 64 + lq * 16) ^ ((row & 7) << 4)));
        sacc[nf] = mfma_bf16(qf[kk], kf, sacc[nf]);
      }
#pragma unroll
      for (int nf = 0; nf < 8; ++nf) {
        const int row = nf * 16 + lr;
        bf16x8 qkf = *(const bf16x8*)(Qlb + row * 256 + ((kk * 64 + lq * 16) ^ ((row & 7) << 4)));
        sacc[nf] = mfma_bf16(ef[kk], qkf, sacc[nf]);
      }
    }
    __builtin_amdgcn_s_setprio(0);

    __builtin_amdgcn_sched_barrier(0);
    __builtin_amdgcn_s_barrier();        // all waves done reading Klb/Qlb
    __builtin_amdgcn_sched_barrier(0);

    // issue KQ(t+1) FIRST (keeps stores younger in FIFO)
#pragma unroll
    for (int p = 0; p < 4; ++p) gload_lds16(ksrc[p] + nkq, Klb + ldso[p]);
#pragma unroll
    for (int p = 0; p < 4; ++p) gload_lds16(qsrc[p] + nkq, Qlb + ldso[p]);
    __builtin_amdgcn_sched_barrier(0);

    // emit `a` directly (S already scaled; never waited on mid-loop)
    {
      const int qrow_base = qi0 + wid * 16 + lq * 4;
#pragma unroll
      for (int nf = 0; nf < 8; ++nf)
#pragma unroll
        for (int r = 0; r < 4; ++r)
          abase[(size_t)(qrow_base + r) * 2048 + kj0 + nf * 16 + lr] = sacc[nf][r];
    }
    __builtin_amdgcn_sched_barrier(0);

    float rmax[4];
#pragma unroll
    for (int r = 0; r < 4; ++r) {
      float m0 = sacc[0][r];
#pragma unroll
      for (int nf = 1; nf < 8; ++nf) m0 = fmaxf(m0, sacc[nf][r]);
      m0 = fmaxf(m0, __shfl_xor(m0, 1));
      m0 = fmaxf(m0, __shfl_xor(m0, 2));
      m0 = fmaxf(m0, __shfl_xor(m0, 4));
      m0 = fmaxf(m0, __shfl_xor(m0, 8));
      rmax[r] = m0;
    }
    bool small = (rmax[0] - M[0] <= 8.f) & (rmax[1] - M[1] <= 8.f) &
                 (rmax[2] - M[2] <= 8.f) & (rmax[3] - M[3] <= 8.f);
    unsigned long long vote = __ballot(small);
    if (vote != ~0ull) {
      float scl[4];
#pragma unroll
      for (int r = 0; r < 4; ++r) {
        float Mn = fmaxf(M[r], rmax[r]);
        scl[r] = __expf(M[r] - Mn);
        M[r] = Mn;
        L[r] *= scl[r];
      }
#pragma unroll
      for (int dn = 0; dn < 8; ++dn)
#pragma unroll
        for (int r = 0; r < 4; ++r) oacc[dn][r] *= scl[r];
    }
    float ml[4];
#pragma unroll
    for (int r = 0; r < 4; ++r) ml[r] = M[r] * L2E;
    float rsum[4] = {0.f, 0.f, 0.f, 0.f};
#pragma unroll
    for (int nf = 0; nf < 8; ++nf)
#pragma unroll
      for (int r = 0; r < 4; ++r) {
        float pv = exp2f(fmaf(sacc[nf][r], L2E, -ml[r]));
        sacc[nf][r] = pv;
        rsum[r] += pv;
      }
    {
      const int prow0 = wid * 16 + lq * 4;
#pragma unroll
      for (int nf = 0; nf < 8; ++nf)
#pragma unroll
        for (int r = 0; r < 4; ++r) {
          const int row = prow0 + r;
          *(unsigned short*)(Plb + row * 256 + (((nf * 16 + lr) * 2) ^ ((row & 7) << 4))) =
              f2bf(sacc[nf][r]);
        }
    }

    // own V(t) landed (KQ(t+1) 8 + stores 32 remain in flight)
    asm volatile("s_waitcnt vmcnt(40)" ::: "memory");
    __builtin_amdgcn_sched_barrier(0);

    __builtin_amdgcn_s_setprio(1);
#pragma unroll
    for (int kk = 0; kk < 4; ++kk) {
      const int prow = wid * 16 + lr;
      bf16x8 pf = *(const bf16x8*)(Plb + prow * 256 + ((kk * 64 + lq * 16) ^ ((prow & 7) << 4)));
#pragma unroll
      for (int dn = 0; dn < 8; ++dn) {
        const int vrow = dn * 16 + lr;
        bf16x8 vf = *(const bf16x8*)(Vlb + vrow * 256 + ((kk * 64 + lq * 16) ^ ((vrow & 7) << 4)));
        oacc[dn] = mfma_bf16(pf, vf, oacc[dn]);
      }
    }
    __builtin_amdgcn_s_setprio(0);

    // rsum cross-lane reduce AFTER PV: the 4-shfl chain hides under MFMA
#pragma unroll
    for (int r = 0; r < 4; ++r) {
      rsum[r] += __shfl_xor(rsum[r], 1);
      rsum[r] += __shfl_xor(rsum[r], 2);
      rsum[r] += __shfl_xor(rsum[r], 4);
      rsum[r] += __shfl_xor(rsum[r], 8);
      L[r] += rsum[r];
    }

    __builtin_amdgcn_sched_barrier(0);
    __builtin_amdgcn_s_barrier();        // all waves done reading Vlb
    __builtin_amdgcn_sched_barrier(0);
#pragma unroll
    for (int p = 0; p < 4; ++p) gload_lds16(vsrc[p] + nv, Vlb + ldso[p]);
    __builtin_amdgcn_sched_barrier(0);
  }

  {
    const int qrow_base = b * 2048 + qi0 + wid * 16 + lq * 4;
#pragma unroll
    for (int dn = 0; dn < 8; ++dn)
#pragma unroll
      for (int r = 0; r < 4; ++r) {
        float v = oacc[dn][r] / L[r];
        ctx[(size_t)(qrow_base + r) * 1024 + bd * 128 + dn * 16 + lr] = f2bf(v);
      }
  }
}

// ---------------- launch ----------------

extern "C" void kernel_launch(void* const* d_in, const int* in_sizes, int n_in,
                              void* d_out, int out_size, void* d_ws, size_t ws_size,
                              hipStream_t stream) {
  const float* x  = (const float*)d_in[0];
  const float* Wq = (const float*)d_in[1];
  const float* bq = (const float*)d_in[2];
  const float* Wk = (const float*)d_in[3];
  const float* bk = (const float*)d_in[4];
  const float* Wv = (const float*)d_in[5];
  const float* bv = (const float*)d_in[6];
  const float* Wo = (const float*)d_in[7];
  const float* bo = (const float*)d_in[8];
  const float* er = (const float*)d_in[9];

  char* ws = (char*)d_ws;
  unsigned short* xb  = (unsigned short*)(ws + 0);          //  8 MB
  unsigned short* Wqb = (unsigned short*)(ws + 8388608);    //  2 MB
  unsigned short* Wkb = (unsigned short*)(ws + 10485760);   //  2 MB
  unsigned short* Wvb = (unsigned short*)(ws + 12582912);   //  2 MB
  unsigned short* Wob = (unsigned short*)(ws + 14680064);   //  2 MB
  unsigned short* Qb  = (unsigned short*)(ws + 16777216);   //  8 MB
  unsigned short* Kb  = (unsigned short*)(ws + 25165824);   //  8 MB
  unsigned short* Vtb = (unsigned short*)(ws + 33554432);   //  8 MB [16][128][2048]
  unsigned short* ctx = (unsigned short*)(ws + 41943040);   //  8 MB
  unsigned short* ert = (unsigned short*)(ws + 50331648);   //  0.5 MB [2048][128]

  float* a_out = (float*)d_out + 4194304;

  prep_all<<<dim3(8448), dim3(256), 0, stream>>>(x, Wq, Wk, Wv, Wo, er,
                                                 xb, Wqb, Wkb, Wvb, Wob, ert);

  gemm_qkv3<<<dim3(32, 8), dim3(512), 0, stream>>>(xb, Wqb, Wkb, Wvb, bq, bk, bv,
                                                   Qb, Kb, Vtb);

  attn_fused<<<dim3(16, 16), dim3(512), 0, stream>>>(Qb, Kb, Vtb, ert, a_out, ctx);

  gemm_bt<<<dim3(32, 8), dim3(512), 0, stream>>>(ctx, Wob, bo, (float*)d_out);
}